// Round 5
// baseline (248.341 us; speedup 1.0000x reference)
//
#include <hip/hip_runtime.h>
#include <hip/hip_bf16.h>
#include <stdint.h>

typedef __bf16 bf16;
typedef __bf16 bf16x4 __attribute__((ext_vector_type(4)));
typedef __bf16 bf16x8 __attribute__((ext_vector_type(8)));
typedef float f32x4 __attribute__((ext_vector_type(4)));
typedef float f32x16 __attribute__((ext_vector_type(16)));

#define D_MODEL 768
#define NUM_HEADS 48
#define HEAD_CH 16
#define INNER 2304
#define BATCH 2
#define SEQLEN 2048
#define M_ROWS (BATCH * SEQLEN)
#define EPSF 1e-6f

// async global->LDS, 16B per lane. LDS dest must be wave-uniform base + lane*16.
__device__ inline void gload_lds16(const void* g, void* l) {
  __builtin_amdgcn_global_load_lds((__attribute__((address_space(1))) void*)(g),
                                   (__attribute__((address_space(3))) void*)(l),
                                   16, 0, 0);
}

// ---------------------------------------------------------------------------
// f32 -> bf16 convert (memory-bound, float4 in / bf16x4 out)
// ---------------------------------------------------------------------------
__global__ __launch_bounds__(256) void cvt_f32_bf16(
    const float* __restrict__ src, bf16* __restrict__ dst, int n4) {
  const int i = blockIdx.x * 256 + threadIdx.x;
  if (i < n4) {
    const float4 v = ((const float4*)src)[i];
    bf16x4 o;
    o[0] = (bf16)v.x; o[1] = (bf16)v.y; o[2] = (bf16)v.z; o[3] = (bf16)v.w;
    ((bf16x4*)dst)[i] = o;
  }
}

// ---------------------------------------------------------------------------
// GEMM: C[m,n] = sum_k A[m,k]*W[n,k] + bias[n] (+ skip[m,n]); A (M,K), W (N,K)
// m97 pattern: 128x128 tile, BK=32, 4 waves each 64x64, global_load_lds x16.
// ---------------------------------------------------------------------------
template <int NCOLS, bool ADD_SKIP, typename CT>
__global__ __launch_bounds__(256) void gemm_bt(
    const bf16* __restrict__ A, const bf16* __restrict__ W,
    const float* __restrict__ bias, const float* __restrict__ skip,
    CT* __restrict__ C, int K) {
  __shared__ __align__(16) bf16 As[128 * 32];
  __shared__ __align__(16) bf16 Bs[128 * 32];
  const int t = threadIdx.x;
  const int lane = t & 63, w = t >> 6;
  const int wm = (w >> 1) * 64, wn = (w & 1) * 64;
  const int row16 = lane & 15, quad = lane >> 4;
  const int m0 = blockIdx.x * 128, n0 = blockIdx.y * 128;

  f32x4 zero4 = {0.f, 0.f, 0.f, 0.f};
  f32x4 acc[4][4];
#pragma unroll
  for (int mi = 0; mi < 4; ++mi)
#pragma unroll
    for (int ni = 0; ni < 4; ++ni) acc[mi][ni] = zero4;

  const int arow = t >> 2;
  const int acol = (t & 3) * 8;
  const bf16* Ab = A + (size_t)m0 * K;
  const bf16* Wb = W + (size_t)n0 * K;

  for (int kt = 0; kt < K; kt += 32) {
    gload_lds16(Ab + (size_t)arow * K + kt + acol, As + t * 8);
    gload_lds16(Ab + (size_t)(64 + arow) * K + kt + acol, As + 2048 + t * 8);
    gload_lds16(Wb + (size_t)arow * K + kt + acol, Bs + t * 8);
    gload_lds16(Wb + (size_t)(64 + arow) * K + kt + acol, Bs + 2048 + t * 8);
    __syncthreads();

    bf16x8 af[4], wf[4];
#pragma unroll
    for (int mi = 0; mi < 4; ++mi)
      af[mi] = *(const bf16x8*)&As[(wm + mi * 16 + row16) * 32 + quad * 8];
#pragma unroll
    for (int ni = 0; ni < 4; ++ni)
      wf[ni] = *(const bf16x8*)&Bs[(wn + ni * 16 + row16) * 32 + quad * 8];
#pragma unroll
    for (int mi = 0; mi < 4; ++mi)
#pragma unroll
      for (int ni = 0; ni < 4; ++ni)
        acc[mi][ni] = __builtin_amdgcn_mfma_f32_16x16x32_bf16(
            af[mi], wf[ni], acc[mi][ni], 0, 0, 0);
    __syncthreads();
  }

#pragma unroll
  for (int mi = 0; mi < 4; ++mi) {
#pragma unroll
    for (int ni = 0; ni < 4; ++ni) {
      const int col = n0 + wn + ni * 16 + row16;
      const float bv = bias[col];
#pragma unroll
      for (int r = 0; r < 4; ++r) {
        const int row = m0 + wm + mi * 16 + quad * 4 + r;
        float v = acc[mi][ni][r] + bv;
        if (ADD_SKIP) v += skip[(size_t)row * NCOLS + col];
        C[(size_t)row * NCOLS + col] = (CT)v;
      }
    }
  }
}

// ---------------------------------------------------------------------------
// K+V causal width-3 conv: head ch 16..31 -> K (B,N,L,16); 32..47 -> V (B,N,16,L)
// ---------------------------------------------------------------------------
__global__ __launch_bounds__(256) void conv_kv(
    const bf16* __restrict__ u, const float* __restrict__ w_sf,
    const float* __restrict__ b_sf, bf16* __restrict__ kk,
    bf16* __restrict__ vv) {
  const int nh = blockIdx.x, b = blockIdx.y, lc = blockIdx.z;
  const int l0 = lc * 128;
  __shared__ __align__(8) bf16 ut[130 * 32];
  const int t = threadIdx.x;
  for (int i = t; i < 130 * 8; i += 256) {
    const int lr = i >> 3, qd = i & 7;
    const int l = l0 - 2 + lr;
    uint2 val;
    val.x = 0u; val.y = 0u;
    if (l >= 0)
      val = *(const uint2*)&u[(size_t)(b * SEQLEN + l) * INNER + nh * 48 + 16 + qd * 4];
    *(uint2*)&ut[lr * 32 + qd * 4] = val;
  }
  __syncthreads();
  const size_t bn = (size_t)(b * NUM_HEADS + nh);
  for (int i = t; i < 128 * 16; i += 256) {
    const int c = i & 15, lr = i >> 4;
    const int e = nh * 48 + 16 + c;
    const float val = w_sf[e * 3 + 0] * (float)ut[lr * 32 + c] +
                      w_sf[e * 3 + 1] * (float)ut[(lr + 1) * 32 + c] +
                      w_sf[e * 3 + 2] * (float)ut[(lr + 2) * 32 + c] + b_sf[e];
    kk[(bn * SEQLEN + l0 + lr) * 16 + c] = (bf16)val;
  }
  for (int i = t; i < 128 * 16; i += 256) {
    const int lr = i & 127, c = i >> 7;
    const int e = nh * 48 + 32 + c;
    const float val = w_sf[e * 3 + 0] * (float)ut[lr * 32 + 16 + c] +
                      w_sf[e * 3 + 1] * (float)ut[(lr + 1) * 32 + 16 + c] +
                      w_sf[e * 3 + 2] * (float)ut[(lr + 2) * 32 + 16 + c] + b_sf[e];
    vv[(bn * 16 + c) * SEQLEN + l0 + lr] = (bf16)val;
  }
}

// ---------------------------------------------------------------------------
// Causal h-weighted attention v3: 128 Q-rows per block, 32 per wave; each wave
// sweeps the full causal KV range (stride 32, prefetch 1). No cross-wave
// reduction. S^T = mfma_32x32x16(K,Q); h via zero-padded hx; PV = 2x16x16x32.
// Grid: (16 chunks reversed, B*NH). Double-buffered per-wave S tile.
// ---------------------------------------------------------------------------
__global__ __launch_bounds__(256) void attn_kernel(
    const bf16* __restrict__ u, const bf16* __restrict__ kk,
    const bf16* __restrict__ vv, const float* __restrict__ w_sf,
    const float* __restrict__ b_sf, const float* __restrict__ hg,
    float* __restrict__ y) {
  const int zc = (int)gridDim.x - 1 - (int)blockIdx.x;  // big chunks first
  const int nh = blockIdx.y % NUM_HEADS, b = blockIdx.y / NUM_HEADS;
  const int lbase = zc * 128;
  __shared__ __align__(16) float hx[2080];           // hx[32+d] = h[d], 0 for d<0
  __shared__ __align__(16) bf16 st[8 * 32 * 40];     // 4 waves x 2 bufs x 32x40
  const int t = threadIdx.x;
  const int hlim = 160 + 128 * zc;  // only the range this block can touch
  for (int i = t; i < hlim; i += 256)
    hx[i] = (i >= 32) ? hg[nh * SEQLEN + i - 32] : 0.f;
  __syncthreads();

  const int w = t >> 6, lane = t & 63;
  const int l31 = lane & 31, hi = lane >> 5;
  const int row16 = lane & 15, quad = lane >> 4;
  const int l0w = lbase + 32 * w;  // this wave's 32 Q rows
  const bf16* ub = u + (size_t)b * SEQLEN * INNER;
  const size_t bn = (size_t)(b * NUM_HEADS + nh);
  const bf16* kb = kk + bn * SEQLEN * 16;
  const bf16* vb = vv + bn * 16 * SEQLEN;

  bf16x8 zf;
#pragma unroll
  for (int j = 0; j < 8; ++j) zf[j] = (bf16)0.f;
  const f32x4 zacc4 = {0.f, 0.f, 0.f, 0.f};
  f32x16 zacc16;
#pragma unroll
  for (int j = 0; j < 16; ++j) zacc16[j] = 0.f;

  // ---- fused Q conv: Q[l0w+l31][ch hi*8..+8] ----
  bf16x8 qf;
  {
    const int cq = nh * 48 + hi * 8;
    const int l = l0w + l31;
    bf16x8 t2 = *(const bf16x8*)&ub[(size_t)l * INNER + cq];
    bf16x8 t1 = (l >= 1) ? *(const bf16x8*)&ub[(size_t)(l - 1) * INNER + cq] : zf;
    bf16x8 t0 = (l >= 2) ? *(const bf16x8*)&ub[(size_t)(l - 2) * INNER + cq] : zf;
#pragma unroll
    for (int j = 0; j < 8; ++j)
      qf[j] = (bf16)(w_sf[(cq + j) * 3 + 0] * (float)t0[j] +
                     w_sf[(cq + j) * 3 + 1] * (float)t1[j] +
                     w_sf[(cq + j) * 3 + 2] * (float)t2[j] + b_sf[cq + j]);
  }

  f32x4 o0 = zacc4, o1 = zacc4;
  const int nsteps = (l0w >> 5) + 1;
  int sbuf = 0;

  bf16x8 kf = *(const bf16x8*)&kb[l31 * 16 + hi * 8];
  bf16x8 vf = *(const bf16x8*)&vb[row16 * SEQLEN + quad * 8];
  for (int s2 = 0; s2 < nsteps; ++s2) {
    const int mc = s2 * 32;
    bf16x8 kf2 = zf, vf2 = zf;
    if (s2 + 1 < nsteps) {  // prefetch next KV chunk
      kf2 = *(const bf16x8*)&kb[(mc + 32 + l31) * 16 + hi * 8];
      vf2 = *(const bf16x8*)&vb[row16 * SEQLEN + mc + 32 + quad * 8];
    }
    // S^T[m-local=rows][l-local=cols]
    f32x16 s = __builtin_amdgcn_mfma_f32_32x32x16_bf16(kf, qf, zacc16, 0, 0, 0);

    bf16* sw = &st[(w * 2 + sbuf) * 32 * 40];
    // h-weight + causal mask (hx zero pad), pack 4 rows -> b64 LDS store
    const int hb0 = 32 + (l0w - mc) + l31 - 4 * hi;
#pragma unroll
    for (int g = 0; g < 4; ++g) {
      const float* hp = &hx[hb0 - 8 * g - 3];  // hp[3-rr] = hx for row rr
      bf16x4 pk;
      pk[0] = (bf16)(s[4 * g + 0] * hp[3]);
      pk[1] = (bf16)(s[4 * g + 1] * hp[2]);
      pk[2] = (bf16)(s[4 * g + 2] * hp[1]);
      pk[3] = (bf16)(s[4 * g + 3] * hp[0]);
      *(bf16x4*)&sw[l31 * 40 + 8 * g + 4 * hi] = pk;
    }
    asm volatile("s_waitcnt lgkmcnt(0)" ::: "memory");  // stores before reads
    // PV: A = S[l][m] (b128), B = V[m][j] frag (shared by both halves)
    const bf16x8 sf0 = *(const bf16x8*)&sw[row16 * 40 + quad * 8];
    const bf16x8 sf1 = *(const bf16x8*)&sw[(row16 + 16) * 40 + quad * 8];
    o0 = __builtin_amdgcn_mfma_f32_16x16x32_bf16(sf0, vf, o0, 0, 0, 0);
    o1 = __builtin_amdgcn_mfma_f32_16x16x32_bf16(sf1, vf, o1, 0, 0, 0);
    kf = kf2; vf = vf2; sbuf ^= 1;
  }

  // direct store: y (B, L, N*HC); o0 rows l0w+quad*4+r, o1 +16; col j = row16
#pragma unroll
  for (int r = 0; r < 4; ++r) {
    const int la = l0w + quad * 4 + r;
    y[((size_t)(b * SEQLEN + la) * NUM_HEADS + nh) * 16 + row16] = o0[r];
    y[((size_t)(b * SEQLEN + la + 16) * NUM_HEADS + nh) * 16 + row16] = o1[r];
  }
}

// ---------------------------------------------------------------------------
// RMSNorm over D=768 per row: y f32 in, yn bf16 out, * norm_w (f32)
// ---------------------------------------------------------------------------
__global__ __launch_bounds__(256) void rmsnorm_k(
    const float* __restrict__ y, const float* __restrict__ nw,
    bf16* __restrict__ yn) {
  const int row = blockIdx.x;
  const int t = threadIdx.x;
  const float* yr = y + (size_t)row * D_MODEL;
  const float v0 = yr[t];
  const float v1 = yr[t + 256];
  const float v2 = yr[t + 512];
  float ss = v0 * v0 + v1 * v1 + v2 * v2;
#pragma unroll
  for (int off = 32; off >= 1; off >>= 1) ss += __shfl_down(ss, off, 64);
  __shared__ float red[4];
  if ((t & 63) == 0) red[t >> 6] = ss;
  __syncthreads();
  const float tot = red[0] + red[1] + red[2] + red[3];
  const float r = rsqrtf(tot * (1.f / 768.f) + EPSF);
  bf16* yo = yn + (size_t)row * D_MODEL;
  yo[t] = (bf16)(v0 * r * nw[t]);
  yo[t + 256] = (bf16)(v1 * r * nw[t + 256]);
  yo[t + 512] = (bf16)(v2 * r * nw[t + 512]);
}

// ---------------------------------------------------------------------------
extern "C" void kernel_launch(void* const* d_in, const int* in_sizes, int n_in,
                              void* d_out, int out_size, void* d_ws,
                              size_t ws_size, hipStream_t stream) {
  const float* inputs = (const float*)d_in[0];
  const float* w_in = (const float*)d_in[1];
  const float* b_in = (const float*)d_in[2];
  const float* w_sf = (const float*)d_in[3];
  const float* b_sf = (const float*)d_in[4];
  const float* hb = (const float*)d_in[5];
  const float* norm_w = (const float*)d_in[6];
  const float* w_out = (const float*)d_in[7];
  const float* b_out = (const float*)d_in[8];

  // ws plan (~36.2 MB, proven):
  //   u      18.9 MB bf16   (alive through attn: Q-conv reads it)
  //   v       6.3 MB bf16
  //   slot    6.3 MB bf16   (in16 for GEMM1 -> k for attn -> yn for GEMM2)
  //   win16   3.5 MB bf16
  //   wout16  1.2 MB bf16
  // y (f32) lives in d_out (dead after rmsnorm, overwritten by GEMM2).
  char* ws = (char*)d_ws;
  const size_t U_B = (size_t)M_ROWS * INNER * 2;
  const size_t V_B = (size_t)BATCH * NUM_HEADS * HEAD_CH * SEQLEN * 2;
  const size_t SLOT_B = (size_t)M_ROWS * D_MODEL * 2;
  const size_t WIN_B = (size_t)INNER * D_MODEL * 2;
  bf16* u = (bf16*)(ws);
  bf16* v = (bf16*)(ws + U_B);
  bf16* in16 = (bf16*)(ws + U_B + V_B);
  bf16* k16 = in16;  // in16 dead after GEMM1
  bf16* yn = in16;   // k dead after attn
  bf16* win16 = (bf16*)(ws + U_B + V_B + SLOT_B);
  bf16* wout16 = (bf16*)(ws + U_B + V_B + SLOT_B + WIN_B);
  float* y = (float*)d_out;
  float* out = (float*)d_out;

  const int n4_in = M_ROWS * D_MODEL / 4;
  const int n4_win = INNER * D_MODEL / 4;
  const int n4_wout = D_MODEL * D_MODEL / 4;
  hipLaunchKernelGGL(cvt_f32_bf16, dim3((n4_in + 255) / 256), dim3(256), 0,
                     stream, inputs, in16, n4_in);
  hipLaunchKernelGGL(cvt_f32_bf16, dim3((n4_win + 255) / 256), dim3(256), 0,
                     stream, w_in, win16, n4_win);
  hipLaunchKernelGGL(cvt_f32_bf16, dim3((n4_wout + 255) / 256), dim3(256), 0,
                     stream, w_out, wout16, n4_wout);

  hipLaunchKernelGGL((gemm_bt<INNER, false, bf16>), dim3(32, 18), dim3(256), 0,
                     stream, in16, win16, b_in, (const float*)nullptr, u, 768);
  hipLaunchKernelGGL(conv_kv, dim3(48, 2, 16), dim3(256), 0, stream, u, w_sf,
                     b_sf, k16, v);
  hipLaunchKernelGGL(attn_kernel, dim3(16, 96), dim3(256), 0, stream, u, k16,
                     v, w_sf, b_sf, hb, y);
  hipLaunchKernelGGL(rmsnorm_k, dim3(M_ROWS), dim3(256), 0, stream, y, norm_w,
                     yn);
  hipLaunchKernelGGL((gemm_bt<D_MODEL, true, float>), dim3(32, 6), dim3(256),
                     0, stream, yn, wout16, b_out, inputs, out, 768);
}

// Round 7
// 235.888 us; speedup vs baseline: 1.0528x; 1.0528x over previous
//
#include <hip/hip_runtime.h>
#include <hip/hip_bf16.h>
#include <stdint.h>

typedef __bf16 bf16;
typedef __bf16 bf16x4 __attribute__((ext_vector_type(4)));
typedef __bf16 bf16x8 __attribute__((ext_vector_type(8)));
typedef float f32x4 __attribute__((ext_vector_type(4)));
typedef float f32x16 __attribute__((ext_vector_type(16)));
// float4 with only 4B alignment guarantee (global gather of hr windows)
typedef float f32x4u __attribute__((ext_vector_type(4), aligned(4)));

#define D_MODEL 768
#define NUM_HEADS 48
#define HEAD_CH 16
#define INNER 2304
#define BATCH 2
#define SEQLEN 2048
#define M_ROWS (BATCH * SEQLEN)
#define HR_N 2088  // 2048 + 31 slack, zero-filled past 2047
#define EPSF 1e-6f

// async global->LDS, 16B per lane. LDS dest must be wave-uniform base + lane*16.
__device__ inline void gload_lds16(const void* g, void* l) {
  __builtin_amdgcn_global_load_lds((__attribute__((address_space(1))) void*)(g),
                                   (__attribute__((address_space(3))) void*)(l),
                                   16, 0, 0);
}

// ---------------------------------------------------------------------------
// f32 -> bf16 convert (memory-bound, float4 in / bf16x4 out)
// ---------------------------------------------------------------------------
__global__ __launch_bounds__(256) void cvt_f32_bf16(
    const float* __restrict__ src, bf16* __restrict__ dst, int n4) {
  const int i = blockIdx.x * 256 + threadIdx.x;
  if (i < n4) {
    const float4 v = ((const float4*)src)[i];
    bf16x4 o;
    o[0] = (bf16)v.x; o[1] = (bf16)v.y; o[2] = (bf16)v.z; o[3] = (bf16)v.w;
    ((bf16x4*)dst)[i] = o;
  }
}

// ---------------------------------------------------------------------------
// hr[nh][i] = h[nh][2047 - i] for i<=2047 else 0  (reversed + zero pad)
// ---------------------------------------------------------------------------
__global__ __launch_bounds__(256) void hrev_k(const float* __restrict__ hg,
                                              float* __restrict__ hr) {
  const int nh = blockIdx.x;
  for (int i = threadIdx.x; i < HR_N; i += 256)
    hr[nh * HR_N + i] = (i <= 2047) ? hg[nh * SEQLEN + 2047 - i] : 0.f;
}

// ---------------------------------------------------------------------------
// GEMM: C[m,n] = sum_k A[m,k]*W[n,k] + bias[n] (+ skip[m,n]); A (M,K), W (N,K)
// m97 pattern: 128x128 tile, BK=32, 4 waves each 64x64, global_load_lds x16.
// ---------------------------------------------------------------------------
template <int NCOLS, bool ADD_SKIP, typename CT>
__global__ __launch_bounds__(256) void gemm_bt(
    const bf16* __restrict__ A, const bf16* __restrict__ W,
    const float* __restrict__ bias, const float* __restrict__ skip,
    CT* __restrict__ C, int K) {
  __shared__ __align__(16) bf16 As[128 * 32];
  __shared__ __align__(16) bf16 Bs[128 * 32];
  const int t = threadIdx.x;
  const int lane = t & 63, w = t >> 6;
  const int wm = (w >> 1) * 64, wn = (w & 1) * 64;
  const int row16 = lane & 15, quad = lane >> 4;
  const int m0 = blockIdx.x * 128, n0 = blockIdx.y * 128;

  f32x4 zero4 = {0.f, 0.f, 0.f, 0.f};
  f32x4 acc[4][4];
#pragma unroll
  for (int mi = 0; mi < 4; ++mi)
#pragma unroll
    for (int ni = 0; ni < 4; ++ni) acc[mi][ni] = zero4;

  const int arow = t >> 2;
  const int acol = (t & 3) * 8;
  const bf16* Ab = A + (size_t)m0 * K;
  const bf16* Wb = W + (size_t)n0 * K;

  for (int kt = 0; kt < K; kt += 32) {
    gload_lds16(Ab + (size_t)arow * K + kt + acol, As + t * 8);
    gload_lds16(Ab + (size_t)(64 + arow) * K + kt + acol, As + 2048 + t * 8);
    gload_lds16(Wb + (size_t)arow * K + kt + acol, Bs + t * 8);
    gload_lds16(Wb + (size_t)(64 + arow) * K + kt + acol, Bs + 2048 + t * 8);
    __syncthreads();

    bf16x8 af[4], wf[4];
#pragma unroll
    for (int mi = 0; mi < 4; ++mi)
      af[mi] = *(const bf16x8*)&As[(wm + mi * 16 + row16) * 32 + quad * 8];
#pragma unroll
    for (int ni = 0; ni < 4; ++ni)
      wf[ni] = *(const bf16x8*)&Bs[(wn + ni * 16 + row16) * 32 + quad * 8];
#pragma unroll
    for (int mi = 0; mi < 4; ++mi)
#pragma unroll
      for (int ni = 0; ni < 4; ++ni)
        acc[mi][ni] = __builtin_amdgcn_mfma_f32_16x16x32_bf16(
            af[mi], wf[ni], acc[mi][ni], 0, 0, 0);
    __syncthreads();
  }

#pragma unroll
  for (int mi = 0; mi < 4; ++mi) {
#pragma unroll
    for (int ni = 0; ni < 4; ++ni) {
      const int col = n0 + wn + ni * 16 + row16;
      const float bv = bias[col];
#pragma unroll
      for (int r = 0; r < 4; ++r) {
        const int row = m0 + wm + mi * 16 + quad * 4 + r;
        float v = acc[mi][ni][r] + bv;
        if (ADD_SKIP) v += skip[(size_t)row * NCOLS + col];
        C[(size_t)row * NCOLS + col] = (CT)v;
      }
    }
  }
}

// ---------------------------------------------------------------------------
// K+V causal width-3 conv: head ch 16..31 -> K (B,N,L,16); 32..47 -> V (B,N,16,L)
// ---------------------------------------------------------------------------
__global__ __launch_bounds__(256) void conv_kv(
    const bf16* __restrict__ u, const float* __restrict__ w_sf,
    const float* __restrict__ b_sf, bf16* __restrict__ kk,
    bf16* __restrict__ vv) {
  const int nh = blockIdx.x, b = blockIdx.y, lc = blockIdx.z;
  const int l0 = lc * 128;
  __shared__ __align__(8) bf16 ut[130 * 32];
  const int t = threadIdx.x;
  for (int i = t; i < 130 * 8; i += 256) {
    const int lr = i >> 3, qd = i & 7;
    const int l = l0 - 2 + lr;
    uint2 val;
    val.x = 0u; val.y = 0u;
    if (l >= 0)
      val = *(const uint2*)&u[(size_t)(b * SEQLEN + l) * INNER + nh * 48 + 16 + qd * 4];
    *(uint2*)&ut[lr * 32 + qd * 4] = val;
  }
  __syncthreads();
  const size_t bn = (size_t)(b * NUM_HEADS + nh);
  for (int i = t; i < 128 * 16; i += 256) {
    const int c = i & 15, lr = i >> 4;
    const int e = nh * 48 + 16 + c;
    const float val = w_sf[e * 3 + 0] * (float)ut[lr * 32 + c] +
                      w_sf[e * 3 + 1] * (float)ut[(lr + 1) * 32 + c] +
                      w_sf[e * 3 + 2] * (float)ut[(lr + 2) * 32 + c] + b_sf[e];
    kk[(bn * SEQLEN + l0 + lr) * 16 + c] = (bf16)val;
  }
  for (int i = t; i < 128 * 16; i += 256) {
    const int lr = i & 127, c = i >> 7;
    const int e = nh * 48 + 32 + c;
    const float val = w_sf[e * 3 + 0] * (float)ut[lr * 32 + 16 + c] +
                      w_sf[e * 3 + 1] * (float)ut[(lr + 1) * 32 + 16 + c] +
                      w_sf[e * 3 + 2] * (float)ut[(lr + 2) * 32 + 16 + c] + b_sf[e];
    vv[(bn * 16 + c) * SEQLEN + l0 + lr] = (bf16)val;
  }
}

// ---------------------------------------------------------------------------
// Causal h-weighted attention v4b: one 32-row Q-tile per block, KV split 4 ways
// across waves (6144 blocks), h served from GLOBAL reversed table hr (16B
// windows, ascending in reg index j -> hv[j] direct; the reversal lives in hr).
// S^T = mfma_32x32x16(K,Q); PV = 2x mfma_16x16x32; cross-wave O reduce in LDS.
// ---------------------------------------------------------------------------
__global__ __launch_bounds__(256) void attn_kernel(
    const bf16* __restrict__ u, const bf16* __restrict__ kk,
    const bf16* __restrict__ vv, const float* __restrict__ w_sf,
    const float* __restrict__ b_sf, const float* __restrict__ hr,
    float* __restrict__ y) {
  const int nh = blockIdx.x, b = blockIdx.y;
  const int q32 = (int)gridDim.z - 1 - (int)blockIdx.z;  // big tiles first
  const int l0 = q32 * 32;
  __shared__ __align__(16) bf16 st[4 * 32 * 40];  // per-wave S-tile / O-redux
  const int t = threadIdx.x;
  const int w = t >> 6, lane = t & 63;
  const int l31 = lane & 31, hi = lane >> 5;
  const int row16 = lane & 15, quad = lane >> 4;
  const bf16* ub = u + (size_t)b * SEQLEN * INNER;
  const size_t bn = (size_t)(b * NUM_HEADS + nh);
  const bf16* kb = kk + bn * SEQLEN * 16;
  const bf16* vb = vv + bn * 16 * SEQLEN;
  const float* hrb = hr + nh * HR_N;

  bf16x8 zf;
#pragma unroll
  for (int j = 0; j < 8; ++j) zf[j] = (bf16)0.f;
  const f32x4 zacc4 = {0.f, 0.f, 0.f, 0.f};
  f32x16 zacc16;
#pragma unroll
  for (int j = 0; j < 16; ++j) zacc16[j] = 0.f;

  // ---- fused Q conv: Q[l0+l31][ch hi*8..+8] ----
  bf16x8 qf;
  {
    const int cq = nh * 48 + hi * 8;
    const int l = l0 + l31;
    bf16x8 t2 = *(const bf16x8*)&ub[(size_t)l * INNER + cq];
    bf16x8 t1 = (l >= 1) ? *(const bf16x8*)&ub[(size_t)(l - 1) * INNER + cq] : zf;
    bf16x8 t0 = (l >= 2) ? *(const bf16x8*)&ub[(size_t)(l - 2) * INNER + cq] : zf;
#pragma unroll
    for (int j = 0; j < 8; ++j)
      qf[j] = (bf16)(w_sf[(cq + j) * 3 + 0] * (float)t0[j] +
                     w_sf[(cq + j) * 3 + 1] * (float)t1[j] +
                     w_sf[(cq + j) * 3 + 2] * (float)t2[j] + b_sf[cq + j]);
  }

  f32x4 o0 = zacc4, o1 = zacc4;
  bf16* sw = &st[w * 32 * 40];

  int mc = w * 32;
  bf16x8 kf = zf, vf = zf;
  if (mc <= l0) {
    kf = *(const bf16x8*)&kb[(mc + l31) * 16 + hi * 8];
    vf = *(const bf16x8*)&vb[row16 * SEQLEN + mc + quad * 8];
  }
  for (; mc <= l0; mc += 128) {
    const int mn = mc + 128;
    bf16x8 kf2 = zf, vf2 = zf;
    if (mn <= l0) {  // prefetch next chunk
      kf2 = *(const bf16x8*)&kb[(mn + l31) * 16 + hi * 8];
      vf2 = *(const bf16x8*)&vb[row16 * SEQLEN + mn + quad * 8];
    }
    // S^T[m-local=rows][l-local=cols] = sum_ch K*Q
    f32x16 s = __builtin_amdgcn_mfma_f32_32x32x16_bf16(kf, qf, zacc16, 0, 0, 0);

    // h[d], d = l_glob - m_glob = (l0-mc)+l31-(4hi+8g+j);
    // hr[i] = h[2047-i] -> i = 2047-d = hbase + 8g + j (ascending in j).
    const int hbase = 2047 - (l0 - mc) - l31 + 4 * hi;
#pragma unroll
    for (int g = 0; g < 4; ++g) {
      const f32x4u hv = *(const f32x4u*)&hrb[hbase + 8 * g];  // hv[j] for reg j
      bf16x4 pk;
      pk[0] = (bf16)(s[4 * g + 0] * hv[0]);
      pk[1] = (bf16)(s[4 * g + 1] * hv[1]);
      pk[2] = (bf16)(s[4 * g + 2] * hv[2]);
      pk[3] = (bf16)(s[4 * g + 3] * hv[3]);
      *(bf16x4*)&sw[l31 * 40 + 8 * g + 4 * hi] = pk;
    }
    asm volatile("s_waitcnt lgkmcnt(0)" ::: "memory");  // stores before reads
    // PV: A = S[l][m] (b128), B = V[m][j] frag (shared by both halves)
    const bf16x8 sf0 = *(const bf16x8*)&sw[row16 * 40 + quad * 8];
    const bf16x8 sf1 = *(const bf16x8*)&sw[(row16 + 16) * 40 + quad * 8];
    o0 = __builtin_amdgcn_mfma_f32_16x16x32_bf16(sf0, vf, o0, 0, 0, 0);
    o1 = __builtin_amdgcn_mfma_f32_16x16x32_bf16(sf1, vf, o1, 0, 0, 0);
    asm volatile("" ::: "memory");  // reads before next-iter stores
    kf = kf2; vf = vf2;
  }

  // per-wave O into own LDS region (f32 32x16), then block reduce
  float* ob = (float*)&st[w * 32 * 40];
#pragma unroll
  for (int r = 0; r < 4; ++r) {
    ob[(quad * 4 + r) * 16 + row16] = o0[r];
    ob[(quad * 4 + r + 16) * 16 + row16] = o1[r];
  }
  __syncthreads();
  for (int i = t; i < 32 * 16; i += 256) {
    const int l = i >> 4, j = i & 15;
    float sum = 0.f;
#pragma unroll
    for (int ww = 0; ww < 4; ++ww)
      sum += ((const float*)&st[ww * 32 * 40])[l * 16 + j];
    y[((size_t)(b * SEQLEN + l0 + l) * NUM_HEADS + nh) * 16 + j] = sum;
  }
}

// ---------------------------------------------------------------------------
// RMSNorm over D=768 per row: y f32 in, yn bf16 out, * norm_w (f32)
// ---------------------------------------------------------------------------
__global__ __launch_bounds__(256) void rmsnorm_k(
    const float* __restrict__ y, const float* __restrict__ nw,
    bf16* __restrict__ yn) {
  const int row = blockIdx.x;
  const int t = threadIdx.x;
  const float* yr = y + (size_t)row * D_MODEL;
  const float v0 = yr[t];
  const float v1 = yr[t + 256];
  const float v2 = yr[t + 512];
  float ss = v0 * v0 + v1 * v1 + v2 * v2;
#pragma unroll
  for (int off = 32; off >= 1; off >>= 1) ss += __shfl_down(ss, off, 64);
  __shared__ float red[4];
  if ((t & 63) == 0) red[t >> 6] = ss;
  __syncthreads();
  const float tot = red[0] + red[1] + red[2] + red[3];
  const float r = rsqrtf(tot * (1.f / 768.f) + EPSF);
  bf16* yo = yn + (size_t)row * D_MODEL;
  yo[t] = (bf16)(v0 * r * nw[t]);
  yo[t + 256] = (bf16)(v1 * r * nw[t + 256]);
  yo[t + 512] = (bf16)(v2 * r * nw[t + 512]);
}

// ---------------------------------------------------------------------------
extern "C" void kernel_launch(void* const* d_in, const int* in_sizes, int n_in,
                              void* d_out, int out_size, void* d_ws,
                              size_t ws_size, hipStream_t stream) {
  const float* inputs = (const float*)d_in[0];
  const float* w_in = (const float*)d_in[1];
  const float* b_in = (const float*)d_in[2];
  const float* w_sf = (const float*)d_in[3];
  const float* b_sf = (const float*)d_in[4];
  const float* hb = (const float*)d_in[5];
  const float* norm_w = (const float*)d_in[6];
  const float* w_out = (const float*)d_in[7];
  const float* b_out = (const float*)d_in[8];

  // ws plan (~36.6 MB):
  //   u      18.9 MB bf16   (alive through attn: Q-conv reads it)
  //   v       6.3 MB bf16
  //   slot    6.3 MB bf16   (in16 for GEMM1 -> k for attn -> yn for GEMM2)
  //   win16   3.5 MB bf16
  //   wout16  1.2 MB bf16
  //   hr      0.4 MB f32    (reversed zero-padded h per head)
  // y (f32) lives in d_out (dead after rmsnorm, overwritten by GEMM2).
  char* ws = (char*)d_ws;
  const size_t U_B = (size_t)M_ROWS * INNER * 2;
  const size_t V_B = (size_t)BATCH * NUM_HEADS * HEAD_CH * SEQLEN * 2;
  const size_t SLOT_B = (size_t)M_ROWS * D_MODEL * 2;
  const size_t WIN_B = (size_t)INNER * D_MODEL * 2;
  const size_t WOUT_B = (size_t)D_MODEL * D_MODEL * 2;
  bf16* u = (bf16*)(ws);
  bf16* v = (bf16*)(ws + U_B);
  bf16* in16 = (bf16*)(ws + U_B + V_B);
  bf16* k16 = in16;  // in16 dead after GEMM1
  bf16* yn = in16;   // k dead after attn
  bf16* win16 = (bf16*)(ws + U_B + V_B + SLOT_B);
  bf16* wout16 = (bf16*)(ws + U_B + V_B + SLOT_B + WIN_B);
  float* hr = (float*)(ws + U_B + V_B + SLOT_B + WIN_B + WOUT_B);
  float* y = (float*)d_out;
  float* out = (float*)d_out;

  const int n4_in = M_ROWS * D_MODEL / 4;
  const int n4_win = INNER * D_MODEL / 4;
  const int n4_wout = D_MODEL * D_MODEL / 4;
  hipLaunchKernelGGL(cvt_f32_bf16, dim3((n4_in + 255) / 256), dim3(256), 0,
                     stream, inputs, in16, n4_in);
  hipLaunchKernelGGL(cvt_f32_bf16, dim3((n4_win + 255) / 256), dim3(256), 0,
                     stream, w_in, win16, n4_win);
  hipLaunchKernelGGL(cvt_f32_bf16, dim3((n4_wout + 255) / 256), dim3(256), 0,
                     stream, w_out, wout16, n4_wout);
  hipLaunchKernelGGL(hrev_k, dim3(NUM_HEADS), dim3(256), 0, stream, hb, hr);

  hipLaunchKernelGGL((gemm_bt<INNER, false, bf16>), dim3(32, 18), dim3(256), 0,
                     stream, in16, win16, b_in, (const float*)nullptr, u, 768);
  hipLaunchKernelGGL(conv_kv, dim3(48, 2, 16), dim3(256), 0, stream, u, w_sf,
                     b_sf, k16, v);
  hipLaunchKernelGGL(attn_kernel, dim3(48, 2, 64), dim3(256), 0, stream, u,
                     k16, v, w_sf, b_sf, hr, y);
  hipLaunchKernelGGL(rmsnorm_k, dim3(M_ROWS), dim3(256), 0, stream, y, norm_w,
                     yn);
  hipLaunchKernelGGL((gemm_bt<D_MODEL, true, float>), dim3(32, 6), dim3(256),
                     0, stream, yn, wout16, b_out, inputs, out, 768);
}